// Round 13
// baseline (167.541 us; speedup 1.0000x reference)
//
#include <hip/hip_runtime.h>
#include <math.h>

#define NSEQ   2048
#define DMODEL 1024
#define NHEADS 16
#define HD     64
#define NJH    2
#define JSPAN  (NSEQ / NJH)

typedef short bf16x8 __attribute__((ext_vector_type(8)));
typedef float f32x4  __attribute__((ext_vector_type(4)));
typedef unsigned short ushort8_t __attribute__((ext_vector_type(8)));

// RTNE float -> bf16 bits
__device__ __forceinline__ unsigned short f2bf(float x) {
    unsigned int u = __builtin_bit_cast(unsigned int, x);
    unsigned int r = (u + 0x7FFFu + ((u >> 16) & 1u)) >> 16;
    return (unsigned short)r;
}

// ---------------------------------------------------------------------------
// Convert inputs to bf16: x(2M)->xb, Wq/Wk/Wv(3x1M)->Wb[3072][1024], Wo->Wob.
// ---------------------------------------------------------------------------
__global__ __launch_bounds__(256) void convert_inputs(
    const float* __restrict__ x,  const float* __restrict__ Wq,
    const float* __restrict__ Wk, const float* __restrict__ Wv,
    const float* __restrict__ Wo,
    unsigned short* __restrict__ xb, unsigned short* __restrict__ Wb,
    unsigned short* __restrict__ Wob)
{
    const size_t i8 = ((size_t)blockIdx.x * 256 + threadIdx.x) * 8;
    const float* src;
    unsigned short* dst;
    if (i8 < (2ull << 20)) {
        src = x + i8;  dst = xb + i8;
    } else if (i8 < (5ull << 20)) {
        const size_t o = i8 - (2ull << 20);
        const size_t s = o >> 20;
        src = (s == 0 ? Wq : (s == 1 ? Wk : Wv)) + (o & ((1u << 20) - 1));
        dst = Wb + o;
    } else {
        const size_t o = i8 - (5ull << 20);
        src = Wo + o;  dst = Wob + o;
    }
    const float4 v0 = *reinterpret_cast<const float4*>(src);
    const float4 v1 = *reinterpret_cast<const float4*>(src + 4);
    ushort8_t r;
    r[0] = f2bf(v0.x); r[1] = f2bf(v0.y); r[2] = f2bf(v0.z); r[3] = f2bf(v0.w);
    r[4] = f2bf(v1.x); r[5] = f2bf(v1.y); r[6] = f2bf(v1.z); r[7] = f2bf(v1.w);
    *reinterpret_cast<ushort8_t*>(dst) = r;
}

// ---------------------------------------------------------------------------
// bf16 MFMA GEMM (B-transposed), BM=128 x BN=64, BK=64; 4 waves stacked in M.
// T14 async-STAGE prefetch (R12-verified). Swizzled-LDS (R7 family).
// ---------------------------------------------------------------------------
template <int QKV>
__global__ __launch_bounds__(256) void gemm_bt_bf16(
    const unsigned short* __restrict__ A, const unsigned short* __restrict__ B,
    float* __restrict__ C0,
    unsigned short* __restrict__ QbO, float* __restrict__ qnO,
    float* __restrict__ cq2O,
    unsigned short* __restrict__ KbO, float* __restrict__ knO,
    float* __restrict__ ckO,
    unsigned short* __restrict__ VbO)
{
    __shared__ unsigned short Ahs[128 * 64];
    __shared__ unsigned short Bhs[64 * 64];

    const int bm   = blockIdx.x * 128;
    const int bn   = blockIdx.y * 64;
    const int t    = threadIdx.x;
    const int wid  = t >> 6;
    const int lane = t & 63;
    const int g    = lane >> 4;
    const int r    = lane & 15;
    const int wm   = wid * 32;           // wave tile 32(M) x 64(N)

    const int sel = QKV ? (bn >> 10) : 0;
    const int bnl = QKV ? (bn & 1023) : bn;

    f32x4 acc[2][4];
#pragma unroll
    for (int i = 0; i < 2; ++i)
#pragma unroll
        for (int j = 0; j < 4; ++j) acc[i][j] = (f32x4){0.f, 0.f, 0.f, 0.f};

    const int srowA = t >> 1;        // 0..127
    const int shalA = t & 1;         // k-half
    const int srowB = t >> 2;        // 0..63
    const int squadB = t & 3;

    const unsigned short* Ag = &A[(size_t)(bm + srowA) * DMODEL + shalA * 32];
    const unsigned short* Bg = &B[(size_t)(bn + srowB) * DMODEL + squadB * 16];

    ushort8_t av[4], bv[2];
#pragma unroll
    for (int c = 0; c < 4; ++c)
        av[c] = *reinterpret_cast<const ushort8_t*>(Ag + c * 8);
#pragma unroll
    for (int c = 0; c < 2; ++c)
        bv[c] = *reinterpret_cast<const ushort8_t*>(Bg + c * 8);

    for (int k0 = 0; k0 < DMODEL; k0 += 64) {
        __syncthreads();
#pragma unroll
        for (int c = 0; c < 4; ++c) {
            const int sw = ((shalA * 4 + c) ^ (srowA & 7)) * 8;
            *reinterpret_cast<ushort8_t*>(&Ahs[srowA * 64 + sw]) = av[c];
        }
#pragma unroll
        for (int c = 0; c < 2; ++c) {
            const int sw = ((squadB * 2 + c) ^ (srowB & 7)) * 8;
            *reinterpret_cast<ushort8_t*>(&Bhs[srowB * 64 + sw]) = bv[c];
        }
        if (k0 + 64 < DMODEL) {   // issue next-tile loads (overlap with MFMAs)
#pragma unroll
            for (int c = 0; c < 4; ++c)
                av[c] = *reinterpret_cast<const ushort8_t*>(
                    Ag + k0 + 64 + c * 8);
#pragma unroll
            for (int c = 0; c < 2; ++c)
                bv[c] = *reinterpret_cast<const ushort8_t*>(
                    Bg + k0 + 64 + c * 8);
        }
        __syncthreads();

#pragma unroll
        for (int dc = 0; dc < 2; ++dc) {
            bf16x8 af[2], bfr[4];
#pragma unroll
            for (int mt = 0; mt < 2; ++mt)
                af[mt] = *reinterpret_cast<const bf16x8*>(
                    &Ahs[(wm + mt * 16 + r) * 64 + ((dc * 4 + g) ^ (r & 7)) * 8]);
#pragma unroll
            for (int nt = 0; nt < 4; ++nt)
                bfr[nt] = *reinterpret_cast<const bf16x8*>(
                    &Bhs[(nt * 16 + r) * 64 + ((dc * 4 + g) ^ (r & 7)) * 8]);
#pragma unroll
            for (int mt = 0; mt < 2; ++mt)
#pragma unroll
                for (int nt = 0; nt < 4; ++nt)
                    acc[mt][nt] = __builtin_amdgcn_mfma_f32_16x16x32_bf16(
                        af[mt], bfr[nt], acc[mt][nt], 0, 0, 0);
        }
    }

    if (QKV) {
        if (sel < 2) {
            unsigned short* Hb = sel ? KbO : QbO;
            float* narr = sel ? knO : qnO;
            float* carr = sel ? ckO : cq2O;
            const int hh = bnl >> 6;   // one head per block (64 cols)
#pragma unroll
            for (int mt = 0; mt < 2; ++mt) {
#pragma unroll
                for (int rg = 0; rg < 4; ++rg) {
                    float ss = 0.f;
#pragma unroll
                    for (int nt = 0; nt < 4; ++nt) {
                        const float v = acc[mt][nt][rg];
                        ss = fmaf(v, v, ss);
                        Hb[(size_t)(bm + wm + mt * 16 + g * 4 + rg) * 1024 +
                           bnl + nt * 16 + r] = f2bf(v);
                    }
                    ss += __shfl_xor(ss, 1, 64);
                    ss += __shfl_xor(ss, 2, 64);
                    ss += __shfl_xor(ss, 4, 64);
                    ss += __shfl_xor(ss, 8, 64);
                    if (r == 0) {
                        const int row = bm + wm + mt * 16 + g * 4 + rg;
                        narr[hh * NSEQ + row] = ss;
                        carr[hh * NSEQ + row] = (sel ? 1.0f : 2.0f) / (1.0f - ss);
                    }
                }
            }
        } else {
#pragma unroll
            for (int mt = 0; mt < 2; ++mt)
#pragma unroll
                for (int nt = 0; nt < 4; ++nt)
#pragma unroll
                    for (int rg = 0; rg < 4; ++rg)
                        VbO[(size_t)(bm + wm + mt * 16 + g * 4 + rg) * 1024 +
                            bnl + nt * 16 + r] = f2bf(acc[mt][nt][rg]);
        }
    } else {
#pragma unroll
        for (int mt = 0; mt < 2; ++mt)
#pragma unroll
            for (int nt = 0; nt < 4; ++nt)
#pragma unroll
                for (int rg = 0; rg < 4; ++rg)
                    C0[(size_t)(bm + wm + mt * 16 + g * 4 + rg) * 1024 +
                       bnl + nt * 16 + r] = acc[mt][nt][rg];
    }
}

// ---------------------------------------------------------------------------
// Per-head V transpose (bf16->bf16): Vt[(h*64+d)*2048 + n] = Vb[n*1024+h*64+d]
// ---------------------------------------------------------------------------
__global__ __launch_bounds__(256) void vt_kernel_bf16(
    const unsigned short* __restrict__ Vb, unsigned short* __restrict__ Vt)
{
    __shared__ unsigned short Vs[64 * 72];
    const int h   = blockIdx.y;
    const int n0  = blockIdx.x * 64;
    const int t   = threadIdx.x;
    const int row = t >> 2;
    const int seg = (t & 3) * 16;

    const unsigned short* src = Vb + (size_t)(n0 + row) * 1024 + h * HD + seg;
    *reinterpret_cast<ushort8_t*>(&Vs[row * 72 + seg]) =
        *reinterpret_cast<const ushort8_t*>(src);
    *reinterpret_cast<ushort8_t*>(&Vs[row * 72 + seg + 8]) =
        *reinterpret_cast<const ushort8_t*>(src + 8);
    __syncthreads();

    ushort8_t a, b;
#pragma unroll
    for (int c = 0; c < 8; ++c) a[c] = Vs[(seg + c) * 72 + row];
#pragma unroll
    for (int c = 0; c < 8; ++c) b[c] = Vs[(seg + 8 + c) * 72 + row];
    unsigned short* dst = Vt + (size_t)(h * HD + row) * NSEQ + n0 + seg;
    *reinterpret_cast<ushort8_t*>(dst)     = a;
    *reinterpret_cast<ushort8_t*>(dst + 8) = b;
}

// ---------------------------------------------------------------------------
// MFMA hyperbolic attention v6: K and V fragments load GLOBAL->REGISTER
// (16B contiguous per lane; K/V tiles are L1-resident, cross-block L2-hot).
// LDS carries only wave-private P and the kn/ck span -> per-wave-tile LDS
// drops 408->~170 cy (the measured m134-derived bottleneck), and the main
// loop has ZERO barriers (waves drift freely, hiding each other's latency).
// Fragment<->element maps identical to verified v3; only transport changed.
// Grid (NSEQ/64, NHEADS, NJH). 4 waves; wave w: q rows [n0+16w,+16).
// ---------------------------------------------------------------------------
__global__ __launch_bounds__(256) void hyp_attn_v6(
    const unsigned short* __restrict__ Qb, const unsigned short* __restrict__ Kb,
    const unsigned short* __restrict__ Vt,
    const float* __restrict__ qn_a, const float* __restrict__ cq2_a,
    const float* __restrict__ kn_a, const float* __restrict__ ck_a,
    float* __restrict__ Opart, float* __restrict__ lpart)
{
    __shared__ unsigned short Ps[4][16 * 64]; // per-wave [q][j-seg swz]
    __shared__ float kns[JSPAN];
    __shared__ float cks[JSPAN];

    const int h    = blockIdx.y;
    const int n0   = blockIdx.x * 64;
    const int jh   = blockIdx.z;
    const int t    = threadIdx.x;
    const int wid  = t >> 6;
    const int lane = t & 63;
    const int g    = lane >> 4;
    const int r    = lane & 15;
    const int qb   = n0 + wid * 16;

    // ---- prologue: Q frags, per-q constants, kn/ck span -> LDS ----
    bf16x8 qf[2];
#pragma unroll
    for (int dc = 0; dc < 2; ++dc)
        qf[dc] = *reinterpret_cast<const bf16x8*>(
            Qb + (size_t)(qb + r) * DMODEL + h * HD + dc * 32 + g * 8);

    float qn_r[4], c2q[4];
#pragma unroll
    for (int rg = 0; rg < 4; ++rg) {
        qn_r[rg] = qn_a[h * NSEQ + qb + g * 4 + rg];
        c2q[rg]  = cq2_a[h * NSEQ + qb + g * 4 + rg];
    }
#pragma unroll
    for (int i = 0; i < JSPAN / 256; ++i) {
        kns[i * 256 + t] = kn_a[h * NSEQ + jh * JSPAN + i * 256 + t];
        cks[i * 256 + t] = ck_a[h * NSEQ + jh * JSPAN + i * 256 + t];
    }
    __syncthreads();   // kns/cks visible; the ONLY block barrier

    f32x4 oacc[4];
#pragma unroll
    for (int nt = 0; nt < 4; ++nt) oacc[nt] = (f32x4){0.f, 0.f, 0.f, 0.f};
    float l_acc[4] = {0.f, 0.f, 0.f, 0.f};

    unsigned short* Pw = &Ps[wid][0];

    // per-lane global bases (16B-contiguous fragment loads)
    const unsigned short* Kg =
        Kb + (size_t)(jh * JSPAN + r) * DMODEL + h * HD + g * 8;
    const unsigned short* Vg =
        Vt + (size_t)(h * HD + r) * NSEQ + jh * JSPAN + g * 8;

    const int ntb = JSPAN / 64;
    for (int tb = 0; tb < ntb; ++tb) {
        const int jl0 = tb * 64;

        // ---- load all K/V fragments for this tile (global -> regs) ----
        bf16x8 kb[4][2], vb[2][4];
#pragma unroll
        for (int jt = 0; jt < 4; ++jt)
#pragma unroll
            for (int dc = 0; dc < 2; ++dc)
                kb[jt][dc] = *reinterpret_cast<const bf16x8*>(
                    Kg + (size_t)(jl0 + jt * 16) * DMODEL + dc * 32);
#pragma unroll
        for (int kc = 0; kc < 2; ++kc)
#pragma unroll
            for (int nt = 0; nt < 4; ++nt)
                vb[kc][nt] = *reinterpret_cast<const bf16x8*>(
                    Vg + (size_t)(nt * 16) * NSEQ + jl0 + kc * 32);

        // ---- S tiles + distance -> w -> P (swizzled wave-private LDS) ----
#pragma unroll
        for (int jt = 0; jt < 4; ++jt) {
            f32x4 sac = (f32x4){0.f, 0.f, 0.f, 0.f};
            sac = __builtin_amdgcn_mfma_f32_16x16x32_bf16(qf[0], kb[jt][0], sac, 0, 0, 0);
            sac = __builtin_amdgcn_mfma_f32_16x16x32_bf16(qf[1], kb[jt][1], sac, 0, 0, 0);
            const int jl = jl0 + jt * 16 + r;
            const float kn_v = kns[jl];
            const float ck_v = cks[jl];
#pragma unroll
            for (int rg = 0; rg < 4; ++rg) {
                const float dsq = fmaf(-2.f, sac[rg], qn_r[rg] + kn_v);
                const float ca  = fmaxf(fmaf(dsq, c2q[rg] * ck_v, 1.f), 1.0f);
                const float s2  = fmaf(ca, ca, -1.f);
                const float wj  = ca - __builtin_amdgcn_sqrtf(s2);
                l_acc[rg] += wj;
                const int qrow = g * 4 + rg;
                Pw[qrow * 64 +
                   ((2 * jt + (r >> 3)) ^ (qrow & 7)) * 8 + (r & 7)] = f2bf(wj);
            }
        }
        // Pw is wave-private: within-wave ds ordering suffices

        // ---- PV: O[q][d] += P . V ----
#pragma unroll
        for (int kc = 0; kc < 2; ++kc) {
            const bf16x8 pa = *reinterpret_cast<const bf16x8*>(
                &Pw[r * 64 + ((kc * 4 + g) ^ (r & 7)) * 8]);
#pragma unroll
            for (int nt = 0; nt < 4; ++nt)
                oacc[nt] = __builtin_amdgcn_mfma_f32_16x16x32_bf16(
                    pa, vb[kc][nt], oacc[nt], 0, 0, 0);
        }
    }

    // ---- l reduce over the 16 r-lanes ----
#pragma unroll
    for (int rg = 0; rg < 4; ++rg) {
        l_acc[rg] += __shfl_xor(l_acc[rg], 1, 64);
        l_acc[rg] += __shfl_xor(l_acc[rg], 2, 64);
        l_acc[rg] += __shfl_xor(l_acc[rg], 4, 64);
        l_acc[rg] += __shfl_xor(l_acc[rg], 8, 64);
    }

    // ---- write partials ----
    float* Op = Opart + (size_t)jh * NSEQ * DMODEL;
#pragma unroll
    for (int nt = 0; nt < 4; ++nt)
#pragma unroll
        for (int rg = 0; rg < 4; ++rg)
            Op[(size_t)(qb + g * 4 + rg) * DMODEL + h * HD + nt * 16 + r] =
                oacc[nt][rg];
    if (r == 0) {
#pragma unroll
        for (int rg = 0; rg < 4; ++rg)
            lpart[(jh * NHEADS + h) * NSEQ + qb + g * 4 + rg] = l_acc[rg];
    }
}

// ---------------------------------------------------------------------------
// Merge j-split partials: Ob = bf16((O0+O1) / (l0+l1)).
// ---------------------------------------------------------------------------
__global__ __launch_bounds__(256) void merge_kernel(
    const float* __restrict__ Opart, const float* __restrict__ lpart,
    unsigned short* __restrict__ Ob)
{
    const size_t i8 = ((size_t)blockIdx.x * 256 + threadIdx.x) * 8;
    if (i8 >= (size_t)NSEQ * DMODEL) return;
    const int n  = (int)(i8 >> 10);
    const int dm = (int)(i8 & 1023);
    const int h  = dm >> 6;
    const float li = 1.0f / (lpart[h * NSEQ + n] +
                             lpart[(NHEADS + h) * NSEQ + n]);
    const float* O0 = Opart + i8;
    const float* O1 = Opart + (size_t)NSEQ * DMODEL + i8;
    ushort8_t o;
#pragma unroll
    for (int c = 0; c < 2; ++c) {
        const float4 a = *reinterpret_cast<const float4*>(O0 + c * 4);
        const float4 b = *reinterpret_cast<const float4*>(O1 + c * 4);
        o[c * 4 + 0] = f2bf((a.x + b.x) * li);
        o[c * 4 + 1] = f2bf((a.y + b.y) * li);
        o[c * 4 + 2] = f2bf((a.z + b.z) * li);
        o[c * 4 + 3] = f2bf((a.w + b.w) * li);
    }
    *reinterpret_cast<ushort8_t*>(Ob + i8) = o;
}

// ---------------------------------------------------------------------------
extern "C" void kernel_launch(void* const* d_in, const int* in_sizes, int n_in,
                              void* d_out, int out_size, void* d_ws, size_t ws_size,
                              hipStream_t stream)
{
    const float* x  = (const float*)d_in[0];
    const float* Wq = (const float*)d_in[1];
    const float* Wk = (const float*)d_in[2];
    const float* Wv = (const float*)d_in[3];
    const float* Wo = (const float*)d_in[4];
    float* out = (float*)d_out;

    char* ws = (char*)d_ws;
    const size_t MB = 1048576;
    unsigned short* xb   = (unsigned short*)(ws);             // 4MB (-> Ob)
    unsigned short* Wb   = (unsigned short*)(ws + 4  * MB);   // 6MB
    unsigned short* Wob  = (unsigned short*)(ws + 10 * MB);   // 2MB
    unsigned short* Qbuf = (unsigned short*)(ws + 12 * MB);   // 4MB
    unsigned short* Kbuf = (unsigned short*)(ws + 16 * MB);   // 4MB
    unsigned short* Vb   = (unsigned short*)(ws + 20 * MB);   // 4MB
    unsigned short* Vt   = (unsigned short*)(ws + 24 * MB);   // 4MB
    float*          qn   = (float*)(ws + 28 * MB);            // 128KB
    float*          cq2  = qn  + NHEADS * NSEQ;
    float*          kn   = cq2 + NHEADS * NSEQ;
    float*          ck   = kn  + NHEADS * NSEQ;
    float*          Opart= (float*)(ws + 29 * MB);            // 16MB
    float*          lpart= (float*)(ws + 45 * MB);            // 256KB
    unsigned short* Ob   = xb;   // xb dead after QKV GEMM

    const dim3 blk(256);

    // 1. fp32 -> bf16 conversions
    convert_inputs<<<3072, blk, 0, stream>>>(x, Wq, Wk, Wv, Wo, xb, Wb, Wob);

    // 2. fused QKV projection + norms in epilogue  [768 blocks]
    gemm_bt_bf16<1><<<dim3(NSEQ / 128, 3072 / 64), blk, 0, stream>>>(
        xb, Wb, nullptr, Qbuf, qn, cq2, Kbuf, kn, ck, Vb);

    // 3. V transpose to [h*64+d][n]
    vt_kernel_bf16<<<dim3(NSEQ / 64, NHEADS), blk, 0, stream>>>(Vb, Vt);

    // 4. attention partials (j-split x2, global->reg K/V)  [1024 blocks]
    hyp_attn_v6<<<dim3(NSEQ / 64, NHEADS, NJH), blk, 0, stream>>>(
        Qbuf, Kbuf, Vt, qn, cq2, kn, ck, Opart, lpart);

    // 5. merge partials -> Ob (bf16)
    merge_kernel<<<(NSEQ * DMODEL / 8 + 255) / 256, blk, 0, stream>>>(
        Opart, lpart, Ob);

    // 6. output projection  [256 blocks]
    gemm_bt_bf16<0><<<dim3(NSEQ / 128, DMODEL / 64), blk, 0, stream>>>(
        Ob, Wob, out, nullptr, nullptr, nullptr,
        nullptr, nullptr, nullptr, nullptr);
}

// Round 14
// 96.292 us; speedup vs baseline: 1.7399x; 1.7399x over previous
//
#include <hip/hip_runtime.h>
#include <math.h>

#define NSEQ   2048
#define DMODEL 1024
#define NHEADS 16
#define HD     64

typedef short bf16x8 __attribute__((ext_vector_type(8)));
typedef float f32x4  __attribute__((ext_vector_type(4)));
typedef unsigned short ushort8_t __attribute__((ext_vector_type(8)));

// RTNE float -> bf16 bits
__device__ __forceinline__ unsigned short f2bf(float x) {
    unsigned int u = __builtin_bit_cast(unsigned int, x);
    unsigned int r = (u + 0x7FFFu + ((u >> 16) & 1u)) >> 16;
    return (unsigned short)r;
}

// ---------------------------------------------------------------------------
// Convert inputs to bf16: x(2M)->xb, Wq/Wk/Wv(3x1M)->Wb[3072][1024], Wo->Wob.
// ---------------------------------------------------------------------------
__global__ __launch_bounds__(256) void convert_inputs(
    const float* __restrict__ x,  const float* __restrict__ Wq,
    const float* __restrict__ Wk, const float* __restrict__ Wv,
    const float* __restrict__ Wo,
    unsigned short* __restrict__ xb, unsigned short* __restrict__ Wb,
    unsigned short* __restrict__ Wob)
{
    const size_t i8 = ((size_t)blockIdx.x * 256 + threadIdx.x) * 8;
    const float* src;
    unsigned short* dst;
    if (i8 < (2ull << 20)) {
        src = x + i8;  dst = xb + i8;
    } else if (i8 < (5ull << 20)) {
        const size_t o = i8 - (2ull << 20);
        const size_t s = o >> 20;
        src = (s == 0 ? Wq : (s == 1 ? Wk : Wv)) + (o & ((1u << 20) - 1));
        dst = Wb + o;
    } else {
        const size_t o = i8 - (5ull << 20);
        src = Wo + o;  dst = Wob + o;
    }
    const float4 v0 = *reinterpret_cast<const float4*>(src);
    const float4 v1 = *reinterpret_cast<const float4*>(src + 4);
    ushort8_t r;
    r[0] = f2bf(v0.x); r[1] = f2bf(v0.y); r[2] = f2bf(v0.z); r[3] = f2bf(v0.w);
    r[4] = f2bf(v1.x); r[5] = f2bf(v1.y); r[6] = f2bf(v1.z); r[7] = f2bf(v1.w);
    *reinterpret_cast<ushort8_t*>(dst) = r;
}

// ---------------------------------------------------------------------------
// bf16 MFMA GEMM (B-transposed), BM=128 x BN=64, BK=64; 4 waves stacked in M.
// T14 async-STAGE prefetch (R12-verified). Swizzled-LDS (R7 family).
// ---------------------------------------------------------------------------
template <int QKV>
__global__ __launch_bounds__(256) void gemm_bt_bf16(
    const unsigned short* __restrict__ A, const unsigned short* __restrict__ B,
    float* __restrict__ C0,
    unsigned short* __restrict__ QbO, float* __restrict__ qnO,
    float* __restrict__ cq2O,
    unsigned short* __restrict__ KbO, float* __restrict__ knO,
    float* __restrict__ ckO,
    unsigned short* __restrict__ VbO)
{
    __shared__ unsigned short Ahs[128 * 64];
    __shared__ unsigned short Bhs[64 * 64];

    const int bm   = blockIdx.x * 128;
    const int bn   = blockIdx.y * 64;
    const int t    = threadIdx.x;
    const int wid  = t >> 6;
    const int lane = t & 63;
    const int g    = lane >> 4;
    const int r    = lane & 15;
    const int wm   = wid * 32;           // wave tile 32(M) x 64(N)

    const int sel = QKV ? (bn >> 10) : 0;
    const int bnl = QKV ? (bn & 1023) : bn;

    f32x4 acc[2][4];
#pragma unroll
    for (int i = 0; i < 2; ++i)
#pragma unroll
        for (int j = 0; j < 4; ++j) acc[i][j] = (f32x4){0.f, 0.f, 0.f, 0.f};

    const int srowA = t >> 1;        // 0..127
    const int shalA = t & 1;         // k-half
    const int srowB = t >> 2;        // 0..63
    const int squadB = t & 3;

    const unsigned short* Ag = &A[(size_t)(bm + srowA) * DMODEL + shalA * 32];
    const unsigned short* Bg = &B[(size_t)(bn + srowB) * DMODEL + squadB * 16];

    ushort8_t av[4], bv[2];
#pragma unroll
    for (int c = 0; c < 4; ++c)
        av[c] = *reinterpret_cast<const ushort8_t*>(Ag + c * 8);
#pragma unroll
    for (int c = 0; c < 2; ++c)
        bv[c] = *reinterpret_cast<const ushort8_t*>(Bg + c * 8);

    for (int k0 = 0; k0 < DMODEL; k0 += 64) {
        __syncthreads();
#pragma unroll
        for (int c = 0; c < 4; ++c) {
            const int sw = ((shalA * 4 + c) ^ (srowA & 7)) * 8;
            *reinterpret_cast<ushort8_t*>(&Ahs[srowA * 64 + sw]) = av[c];
        }
#pragma unroll
        for (int c = 0; c < 2; ++c) {
            const int sw = ((squadB * 2 + c) ^ (srowB & 7)) * 8;
            *reinterpret_cast<ushort8_t*>(&Bhs[srowB * 64 + sw]) = bv[c];
        }
        if (k0 + 64 < DMODEL) {   // issue next-tile loads (overlap with MFMAs)
#pragma unroll
            for (int c = 0; c < 4; ++c)
                av[c] = *reinterpret_cast<const ushort8_t*>(
                    Ag + k0 + 64 + c * 8);
#pragma unroll
            for (int c = 0; c < 2; ++c)
                bv[c] = *reinterpret_cast<const ushort8_t*>(
                    Bg + k0 + 64 + c * 8);
        }
        __syncthreads();

#pragma unroll
        for (int dc = 0; dc < 2; ++dc) {
            bf16x8 af[2], bfr[4];
#pragma unroll
            for (int mt = 0; mt < 2; ++mt)
                af[mt] = *reinterpret_cast<const bf16x8*>(
                    &Ahs[(wm + mt * 16 + r) * 64 + ((dc * 4 + g) ^ (r & 7)) * 8]);
#pragma unroll
            for (int nt = 0; nt < 4; ++nt)
                bfr[nt] = *reinterpret_cast<const bf16x8*>(
                    &Bhs[(nt * 16 + r) * 64 + ((dc * 4 + g) ^ (r & 7)) * 8]);
#pragma unroll
            for (int mt = 0; mt < 2; ++mt)
#pragma unroll
                for (int nt = 0; nt < 4; ++nt)
                    acc[mt][nt] = __builtin_amdgcn_mfma_f32_16x16x32_bf16(
                        af[mt], bfr[nt], acc[mt][nt], 0, 0, 0);
        }
    }

    if (QKV) {
        if (sel < 2) {
            unsigned short* Hb = sel ? KbO : QbO;
            float* narr = sel ? knO : qnO;
            float* carr = sel ? ckO : cq2O;
            const int hh = bnl >> 6;   // one head per block (64 cols)
#pragma unroll
            for (int mt = 0; mt < 2; ++mt) {
#pragma unroll
                for (int rg = 0; rg < 4; ++rg) {
                    float ss = 0.f;
#pragma unroll
                    for (int nt = 0; nt < 4; ++nt) {
                        const float v = acc[mt][nt][rg];
                        ss = fmaf(v, v, ss);
                        Hb[(size_t)(bm + wm + mt * 16 + g * 4 + rg) * 1024 +
                           bnl + nt * 16 + r] = f2bf(v);
                    }
                    ss += __shfl_xor(ss, 1, 64);
                    ss += __shfl_xor(ss, 2, 64);
                    ss += __shfl_xor(ss, 4, 64);
                    ss += __shfl_xor(ss, 8, 64);
                    if (r == 0) {
                        const int row = bm + wm + mt * 16 + g * 4 + rg;
                        narr[hh * NSEQ + row] = ss;
                        carr[hh * NSEQ + row] = (sel ? 1.0f : 2.0f) / (1.0f - ss);
                    }
                }
            }
        } else {
#pragma unroll
            for (int mt = 0; mt < 2; ++mt)
#pragma unroll
                for (int nt = 0; nt < 4; ++nt)
#pragma unroll
                    for (int rg = 0; rg < 4; ++rg)
                        VbO[(size_t)(bm + wm + mt * 16 + g * 4 + rg) * 1024 +
                            bnl + nt * 16 + r] = f2bf(acc[mt][nt][rg]);
        }
    } else {
#pragma unroll
        for (int mt = 0; mt < 2; ++mt)
#pragma unroll
            for (int nt = 0; nt < 4; ++nt)
#pragma unroll
                for (int rg = 0; rg < 4; ++rg)
                    C0[(size_t)(bm + wm + mt * 16 + g * 4 + rg) * 1024 +
                       bnl + nt * 16 + r] = acc[mt][nt][rg];
    }
}

// ---------------------------------------------------------------------------
// Per-head V transpose (bf16->bf16): Vt[(h*64+d)*2048 + n] = Vb[n*1024+h*64+d]
// ---------------------------------------------------------------------------
__global__ __launch_bounds__(256) void vt_kernel_bf16(
    const unsigned short* __restrict__ Vb, unsigned short* __restrict__ Vt)
{
    __shared__ unsigned short Vs[64 * 72];
    const int h   = blockIdx.y;
    const int n0  = blockIdx.x * 64;
    const int t   = threadIdx.x;
    const int row = t >> 2;
    const int seg = (t & 3) * 16;

    const unsigned short* src = Vb + (size_t)(n0 + row) * 1024 + h * HD + seg;
    *reinterpret_cast<ushort8_t*>(&Vs[row * 72 + seg]) =
        *reinterpret_cast<const ushort8_t*>(src);
    *reinterpret_cast<ushort8_t*>(&Vs[row * 72 + seg + 8]) =
        *reinterpret_cast<const ushort8_t*>(src + 8);
    __syncthreads();

    ushort8_t a, b;
#pragma unroll
    for (int c = 0; c < 8; ++c) a[c] = Vs[(seg + c) * 72 + row];
#pragma unroll
    for (int c = 0; c < 8; ++c) b[c] = Vs[(seg + 8 + c) * 72 + row];
    unsigned short* dst = Vt + (size_t)(h * HD + row) * NSEQ + n0 + seg;
    *reinterpret_cast<ushort8_t*>(dst)     = a;
    *reinterpret_cast<ushort8_t*>(dst + 8) = b;
}

// ---------------------------------------------------------------------------
// MFMA hyperbolic attention v7: v5's verified transport (coalesced LDS
// staging + T14 prefetch + swizzled reads), but BM=128 q-rows per block —
// each wave owns 32 q-rows (2 subtiles of 16), so every K/V fragment read
// from LDS feeds 2 MFMAs. LDS cycles per output ~1.6x lower than v5.
// Grid (NSEQ/128, NHEADS, NJH). 4 waves.
// ---------------------------------------------------------------------------
template <int JSPAN>
__global__ __launch_bounds__(256) void hyp_attn_v7(
    const unsigned short* __restrict__ Qb, const unsigned short* __restrict__ Kb,
    const unsigned short* __restrict__ Vt,
    const float* __restrict__ qn_a, const float* __restrict__ cq2_a,
    const float* __restrict__ kn_a, const float* __restrict__ ck_a,
    float* __restrict__ Opart, float* __restrict__ lpart)
{
    __shared__ unsigned short Khs[64 * 64];     // [j][k-seg swz]
    __shared__ unsigned short Vts[64 * 64];     // [d][j-seg swz]
    __shared__ unsigned short Ps[4][32 * 64];   // per-wave [q(32)][j-seg swz]
    __shared__ float kns[JSPAN];
    __shared__ float cks[JSPAN];

    const int h    = blockIdx.y;
    const int n0   = blockIdx.x * 128;
    const int jh   = blockIdx.z;
    const int t    = threadIdx.x;
    const int wid  = t >> 6;
    const int lane = t & 63;
    const int g    = lane >> 4;
    const int r    = lane & 15;
    const int qb   = n0 + wid * 32;        // wave owns 32 q-rows

    // ---- prologue: Q frags (2 subtiles), per-q constants, kn/ck -> LDS ----
    bf16x8 qf[2][2];
#pragma unroll
    for (int s = 0; s < 2; ++s)
#pragma unroll
        for (int dc = 0; dc < 2; ++dc)
            qf[s][dc] = *reinterpret_cast<const bf16x8*>(
                Qb + (size_t)(qb + s * 16 + r) * DMODEL + h * HD + dc * 32 + g * 8);

    float qn_r[2][4], c2q[2][4];
#pragma unroll
    for (int s = 0; s < 2; ++s)
#pragma unroll
        for (int rg = 0; rg < 4; ++rg) {
            qn_r[s][rg] = qn_a[h * NSEQ + qb + s * 16 + g * 4 + rg];
            c2q[s][rg]  = cq2_a[h * NSEQ + qb + s * 16 + g * 4 + rg];
        }
#pragma unroll
    for (int i = 0; i < JSPAN / 256; ++i) {
        kns[i * 256 + t] = kn_a[h * NSEQ + jh * JSPAN + i * 256 + t];
        cks[i * 256 + t] = ck_a[h * NSEQ + jh * JSPAN + i * 256 + t];
    }

    f32x4 oacc[2][4];
#pragma unroll
    for (int s = 0; s < 2; ++s)
#pragma unroll
        for (int nt = 0; nt < 4; ++nt) oacc[s][nt] = (f32x4){0.f, 0.f, 0.f, 0.f};
    float l_acc[2][4] = {{0.f, 0.f, 0.f, 0.f}, {0.f, 0.f, 0.f, 0.f}};

    const int srow = t >> 2;
    const int c0   = (t & 3) * 2;
    const int sw0  = (c0 ^ (srow & 7)) * 8;
    const int sw1  = ((c0 + 1) ^ (srow & 7)) * 8;
    const int sg   = (t & 3) * 16;
    unsigned short* Pw = &Ps[wid][0];

    const unsigned short* Kg = Kb + (size_t)(jh * JSPAN + srow) * DMODEL + h * HD + sg;
    const unsigned short* Vg = Vt + (size_t)(h * HD + srow) * NSEQ + jh * JSPAN + sg;

    // prefetch tile 0 into regs
    ushort8_t kr0 = *reinterpret_cast<const ushort8_t*>(Kg);
    ushort8_t kr1 = *reinterpret_cast<const ushort8_t*>(Kg + 8);
    ushort8_t vr0 = *reinterpret_cast<const ushort8_t*>(Vg);
    ushort8_t vr1 = *reinterpret_cast<const ushort8_t*>(Vg + 8);

    const int ntb = JSPAN / 64;
    for (int tb = 0; tb < ntb; ++tb) {
        __syncthreads();   // prev tile consumed; (tb=0) kns/cks visible
        *reinterpret_cast<ushort8_t*>(&Khs[srow * 64 + sw0]) = kr0;
        *reinterpret_cast<ushort8_t*>(&Khs[srow * 64 + sw1]) = kr1;
        *reinterpret_cast<ushort8_t*>(&Vts[srow * 64 + sw0]) = vr0;
        *reinterpret_cast<ushort8_t*>(&Vts[srow * 64 + sw1]) = vr1;
        if (tb + 1 < ntb) {   // T14: next-tile loads overlap with compute
            const unsigned short* kn_ = Kg + (size_t)(tb + 1) * 64 * DMODEL;
            const unsigned short* vn_ = Vg + (tb + 1) * 64;
            kr0 = *reinterpret_cast<const ushort8_t*>(kn_);
            kr1 = *reinterpret_cast<const ushort8_t*>(kn_ + 8);
            vr0 = *reinterpret_cast<const ushort8_t*>(vn_);
            vr1 = *reinterpret_cast<const ushort8_t*>(vn_ + 8);
        }
        __syncthreads();

        // ---- S tiles (2 subtiles share each K fragment) + distance -> P ----
#pragma unroll
        for (int jt = 0; jt < 4; ++jt) {
            f32x4 sac0 = (f32x4){0.f, 0.f, 0.f, 0.f};
            f32x4 sac1 = (f32x4){0.f, 0.f, 0.f, 0.f};
#pragma unroll
            for (int dc = 0; dc < 2; ++dc) {
                const bf16x8 kb = *reinterpret_cast<const bf16x8*>(
                    &Khs[(jt * 16 + r) * 64 + ((dc * 4 + g) ^ (r & 7)) * 8]);
                sac0 = __builtin_amdgcn_mfma_f32_16x16x32_bf16(qf[0][dc], kb, sac0, 0, 0, 0);
                sac1 = __builtin_amdgcn_mfma_f32_16x16x32_bf16(qf[1][dc], kb, sac1, 0, 0, 0);
            }
            const int jl = tb * 64 + jt * 16 + r;
            const float kn_v = kns[jl];
            const float ck_v = cks[jl];
#pragma unroll
            for (int s = 0; s < 2; ++s) {
                const f32x4 sac = s ? sac1 : sac0;
#pragma unroll
                for (int rg = 0; rg < 4; ++rg) {
                    const float dsq = fmaf(-2.f, sac[rg], qn_r[s][rg] + kn_v);
                    const float ca  = fmaxf(fmaf(dsq, c2q[s][rg] * ck_v, 1.f), 1.0f);
                    const float s2  = fmaf(ca, ca, -1.f);
                    const float wj  = ca - __builtin_amdgcn_sqrtf(s2);
                    l_acc[s][rg] += wj;
                    const int qrow = s * 16 + g * 4 + rg;
                    Pw[qrow * 64 +
                       ((2 * jt + (r >> 3)) ^ (qrow & 7)) * 8 + (r & 7)] = f2bf(wj);
                }
            }
        }
        // Pw is wave-private: within-wave ds ordering suffices

        // ---- PV: each V fragment feeds both subtiles ----
#pragma unroll
        for (int kc = 0; kc < 2; ++kc) {
            const bf16x8 pa0 = *reinterpret_cast<const bf16x8*>(
                &Pw[(0 * 16 + r) * 64 + ((kc * 4 + g) ^ (r & 7)) * 8]);
            const bf16x8 pa1 = *reinterpret_cast<const bf16x8*>(
                &Pw[(1 * 16 + r) * 64 + ((kc * 4 + g) ^ (r & 7)) * 8]);
#pragma unroll
            for (int nt = 0; nt < 4; ++nt) {
                const bf16x8 vb = *reinterpret_cast<const bf16x8*>(
                    &Vts[(nt * 16 + r) * 64 + ((kc * 4 + g) ^ (r & 7)) * 8]);
                oacc[0][nt] = __builtin_amdgcn_mfma_f32_16x16x32_bf16(pa0, vb, oacc[0][nt], 0, 0, 0);
                oacc[1][nt] = __builtin_amdgcn_mfma_f32_16x16x32_bf16(pa1, vb, oacc[1][nt], 0, 0, 0);
            }
        }
    }

    // ---- l reduce over the 16 r-lanes ----
#pragma unroll
    for (int s = 0; s < 2; ++s)
#pragma unroll
        for (int rg = 0; rg < 4; ++rg) {
            l_acc[s][rg] += __shfl_xor(l_acc[s][rg], 1, 64);
            l_acc[s][rg] += __shfl_xor(l_acc[s][rg], 2, 64);
            l_acc[s][rg] += __shfl_xor(l_acc[s][rg], 4, 64);
            l_acc[s][rg] += __shfl_xor(l_acc[s][rg], 8, 64);
        }

    // ---- write partials ----
    float* Op = Opart + (size_t)jh * NSEQ * DMODEL;
#pragma unroll
    for (int s = 0; s < 2; ++s)
#pragma unroll
        for (int nt = 0; nt < 4; ++nt)
#pragma unroll
            for (int rg = 0; rg < 4; ++rg)
                Op[(size_t)(qb + s * 16 + g * 4 + rg) * DMODEL + h * HD + nt * 16 + r] =
                    oacc[s][nt][rg];
    if (r == 0) {
#pragma unroll
        for (int s = 0; s < 2; ++s)
#pragma unroll
            for (int rg = 0; rg < 4; ++rg)
                lpart[(jh * NHEADS + h) * NSEQ + qb + s * 16 + g * 4 + rg] =
                    l_acc[s][rg];
    }
}

// ---------------------------------------------------------------------------
// Merge j-split partials: Ob = bf16(sum_p O_p / sum_p l_p).
// ---------------------------------------------------------------------------
__global__ __launch_bounds__(256) void merge_kernel(
    const float* __restrict__ Opart, const float* __restrict__ lpart,
    unsigned short* __restrict__ Ob, int njh)
{
    const size_t i8 = ((size_t)blockIdx.x * 256 + threadIdx.x) * 8;
    if (i8 >= (size_t)NSEQ * DMODEL) return;
    const int n  = (int)(i8 >> 10);
    const int dm = (int)(i8 & 1023);
    const int h  = dm >> 6;
    float lsum = 0.f;
    for (int p = 0; p < njh; ++p)
        lsum += lpart[(p * NHEADS + h) * NSEQ + n];
    const float li = 1.0f / lsum;
    float s[8] = {0.f, 0.f, 0.f, 0.f, 0.f, 0.f, 0.f, 0.f};
    for (int p = 0; p < njh; ++p) {
        const float* Opp = Opart + (size_t)p * NSEQ * DMODEL + i8;
#pragma unroll
        for (int c = 0; c < 2; ++c) {
            const float4 a = *reinterpret_cast<const float4*>(Opp + c * 4);
            s[c * 4 + 0] += a.x; s[c * 4 + 1] += a.y;
            s[c * 4 + 2] += a.z; s[c * 4 + 3] += a.w;
        }
    }
    ushort8_t o;
#pragma unroll
    for (int c = 0; c < 8; ++c) o[c] = f2bf(s[c] * li);
    *reinterpret_cast<ushort8_t*>(Ob + i8) = o;
}

// ---------------------------------------------------------------------------
extern "C" void kernel_launch(void* const* d_in, const int* in_sizes, int n_in,
                              void* d_out, int out_size, void* d_ws, size_t ws_size,
                              hipStream_t stream)
{
    const float* x  = (const float*)d_in[0];
    const float* Wq = (const float*)d_in[1];
    const float* Wk = (const float*)d_in[2];
    const float* Wv = (const float*)d_in[3];
    const float* Wo = (const float*)d_in[4];
    float* out = (float*)d_out;

    char* ws = (char*)d_ws;
    const size_t MB = 1048576;
    unsigned short* xb   = (unsigned short*)(ws);             // 4MB (-> Ob)
    unsigned short* Wb   = (unsigned short*)(ws + 4  * MB);   // 6MB
    unsigned short* Wob  = (unsigned short*)(ws + 10 * MB);   // 2MB
    unsigned short* Qbuf = (unsigned short*)(ws + 12 * MB);   // 4MB
    unsigned short* Kbuf = (unsigned short*)(ws + 16 * MB);   // 4MB
    unsigned short* Vb   = (unsigned short*)(ws + 20 * MB);   // 4MB
    unsigned short* Vt   = (unsigned short*)(ws + 24 * MB);   // 4MB
    float*          qn   = (float*)(ws + 28 * MB);            // 128KB
    float*          cq2  = qn  + NHEADS * NSEQ;
    float*          kn   = cq2 + NHEADS * NSEQ;
    float*          ck   = kn  + NHEADS * NSEQ;
    float*          Opart= (float*)(ws + 29 * MB);            // njh*8MB
    unsigned short* Ob   = xb;   // xb dead after QKV GEMM

    const int njh = (ws_size >= 63 * MB) ? 4 : 2;
    float* lpart = (float*)(ws + (29 + (size_t)njh * 8) * MB);

    const dim3 blk(256);

    // 1. fp32 -> bf16 conversions
    convert_inputs<<<3072, blk, 0, stream>>>(x, Wq, Wk, Wv, Wo, xb, Wb, Wob);

    // 2. fused QKV projection + norms in epilogue  [768 blocks]
    gemm_bt_bf16<1><<<dim3(NSEQ / 128, 3072 / 64), blk, 0, stream>>>(
        xb, Wb, nullptr, Qbuf, qn, cq2, Kbuf, kn, ck, Vb);

    // 3. V transpose to [h*64+d][n]
    vt_kernel_bf16<<<dim3(NSEQ / 64, NHEADS), blk, 0, stream>>>(Vb, Vt);

    // 4. attention partials (BM=128, j-split x njh)
    if (njh == 4)
        hyp_attn_v7<512><<<dim3(NSEQ / 128, NHEADS, 4), blk, 0, stream>>>(
            Qbuf, Kbuf, Vt, qn, cq2, kn, ck, Opart, lpart);
    else
        hyp_attn_v7<1024><<<dim3(NSEQ / 128, NHEADS, 2), blk, 0, stream>>>(
            Qbuf, Kbuf, Vt, qn, cq2, kn, ck, Opart, lpart);

    // 5. merge partials -> Ob (bf16)
    merge_kernel<<<(NSEQ * DMODEL / 8 + 255) / 256, blk, 0, stream>>>(
        Opart, lpart, Ob, njh);

    // 6. output projection  [256 blocks]
    gemm_bt_bf16<0><<<dim3(NSEQ / 128, DMODEL / 64), blk, 0, stream>>>(
        Ob, Wob, out, nullptr, nullptr, nullptr,
        nullptr, nullptr, nullptr, nullptr);
}

// Round 15
// 92.100 us; speedup vs baseline: 1.8191x; 1.0455x over previous
//
#include <hip/hip_runtime.h>
#include <math.h>

#define NSEQ   2048
#define DMODEL 1024
#define NHEADS 16
#define HD     64
#define NJH    2
#define JSPAN  (NSEQ / NJH)

typedef short bf16x8 __attribute__((ext_vector_type(8)));
typedef float f32x4  __attribute__((ext_vector_type(4)));
typedef unsigned short ushort8_t __attribute__((ext_vector_type(8)));

// RTNE float -> bf16 bits
__device__ __forceinline__ unsigned short f2bf(float x) {
    unsigned int u = __builtin_bit_cast(unsigned int, x);
    unsigned int r = (u + 0x7FFFu + ((u >> 16) & 1u)) >> 16;
    return (unsigned short)r;
}

// ---------------------------------------------------------------------------
// Convert inputs to bf16: x(2M)->xb, Wq/Wk/Wv(3x1M)->Wb[3072][1024], Wo->Wob.
// ---------------------------------------------------------------------------
__global__ __launch_bounds__(256) void convert_inputs(
    const float* __restrict__ x,  const float* __restrict__ Wq,
    const float* __restrict__ Wk, const float* __restrict__ Wv,
    const float* __restrict__ Wo,
    unsigned short* __restrict__ xb, unsigned short* __restrict__ Wb,
    unsigned short* __restrict__ Wob)
{
    const size_t i8 = ((size_t)blockIdx.x * 256 + threadIdx.x) * 8;
    const float* src;
    unsigned short* dst;
    if (i8 < (2ull << 20)) {
        src = x + i8;  dst = xb + i8;
    } else if (i8 < (5ull << 20)) {
        const size_t o = i8 - (2ull << 20);
        const size_t s = o >> 20;
        src = (s == 0 ? Wq : (s == 1 ? Wk : Wv)) + (o & ((1u << 20) - 1));
        dst = Wb + o;
    } else {
        const size_t o = i8 - (5ull << 20);
        src = Wo + o;  dst = Wob + o;
    }
    const float4 v0 = *reinterpret_cast<const float4*>(src);
    const float4 v1 = *reinterpret_cast<const float4*>(src + 4);
    ushort8_t r;
    r[0] = f2bf(v0.x); r[1] = f2bf(v0.y); r[2] = f2bf(v0.z); r[3] = f2bf(v0.w);
    r[4] = f2bf(v1.x); r[5] = f2bf(v1.y); r[6] = f2bf(v1.z); r[7] = f2bf(v1.w);
    *reinterpret_cast<ushort8_t*>(dst) = r;
}

// ---------------------------------------------------------------------------
// bf16 MFMA GEMM (B-transposed), BM=128 x BN=64, BK=64; 4 waves stacked in M.
// T14 async-STAGE prefetch (R12-verified). Swizzled-LDS (R7 family).
// QKV=1: cols 0-1023 (Q): bf16 out + qnc2 float2{qn, 2/(1-qn)};
//        cols 1024-2047 (K): bf16 out + knck float2{kn, 1/(1-kn)};
//        cols 2048-3071 (V): bf16 out TRANSPOSED directly into Vt[dm][n]
//        (rg-consecutive in n -> ushort4 stores; vt kernel eliminated).
// QKV=0: plain f32 output C0 (N=1024).
// ---------------------------------------------------------------------------
template <int QKV>
__global__ __launch_bounds__(256) void gemm_bt_bf16(
    const unsigned short* __restrict__ A, const unsigned short* __restrict__ B,
    float* __restrict__ C0,
    unsigned short* __restrict__ QbO, float2* __restrict__ qnc2O,
    unsigned short* __restrict__ KbO, float2* __restrict__ knckO,
    unsigned short* __restrict__ VtO)
{
    __shared__ unsigned short Ahs[128 * 64];
    __shared__ unsigned short Bhs[64 * 64];

    const int bm   = blockIdx.x * 128;
    const int bn   = blockIdx.y * 64;
    const int t    = threadIdx.x;
    const int wid  = t >> 6;
    const int lane = t & 63;
    const int g    = lane >> 4;
    const int r    = lane & 15;
    const int wm   = wid * 32;           // wave tile 32(M) x 64(N)

    const int sel = QKV ? (bn >> 10) : 0;
    const int bnl = QKV ? (bn & 1023) : bn;

    f32x4 acc[2][4];
#pragma unroll
    for (int i = 0; i < 2; ++i)
#pragma unroll
        for (int j = 0; j < 4; ++j) acc[i][j] = (f32x4){0.f, 0.f, 0.f, 0.f};

    const int srowA = t >> 1;        // 0..127
    const int shalA = t & 1;         // k-half
    const int srowB = t >> 2;        // 0..63
    const int squadB = t & 3;

    const unsigned short* Ag = &A[(size_t)(bm + srowA) * DMODEL + shalA * 32];
    const unsigned short* Bg = &B[(size_t)(bn + srowB) * DMODEL + squadB * 16];

    ushort8_t av[4], bv[2];
#pragma unroll
    for (int c = 0; c < 4; ++c)
        av[c] = *reinterpret_cast<const ushort8_t*>(Ag + c * 8);
#pragma unroll
    for (int c = 0; c < 2; ++c)
        bv[c] = *reinterpret_cast<const ushort8_t*>(Bg + c * 8);

    for (int k0 = 0; k0 < DMODEL; k0 += 64) {
        __syncthreads();
#pragma unroll
        for (int c = 0; c < 4; ++c) {
            const int sw = ((shalA * 4 + c) ^ (srowA & 7)) * 8;
            *reinterpret_cast<ushort8_t*>(&Ahs[srowA * 64 + sw]) = av[c];
        }
#pragma unroll
        for (int c = 0; c < 2; ++c) {
            const int sw = ((squadB * 2 + c) ^ (srowB & 7)) * 8;
            *reinterpret_cast<ushort8_t*>(&Bhs[srowB * 64 + sw]) = bv[c];
        }
        if (k0 + 64 < DMODEL) {   // issue next-tile loads (overlap with MFMAs)
#pragma unroll
            for (int c = 0; c < 4; ++c)
                av[c] = *reinterpret_cast<const ushort8_t*>(
                    Ag + k0 + 64 + c * 8);
#pragma unroll
            for (int c = 0; c < 2; ++c)
                bv[c] = *reinterpret_cast<const ushort8_t*>(
                    Bg + k0 + 64 + c * 8);
        }
        __syncthreads();

#pragma unroll
        for (int dc = 0; dc < 2; ++dc) {
            bf16x8 af[2], bfr[4];
#pragma unroll
            for (int mt = 0; mt < 2; ++mt)
                af[mt] = *reinterpret_cast<const bf16x8*>(
                    &Ahs[(wm + mt * 16 + r) * 64 + ((dc * 4 + g) ^ (r & 7)) * 8]);
#pragma unroll
            for (int nt = 0; nt < 4; ++nt)
                bfr[nt] = *reinterpret_cast<const bf16x8*>(
                    &Bhs[(nt * 16 + r) * 64 + ((dc * 4 + g) ^ (r & 7)) * 8]);
#pragma unroll
            for (int mt = 0; mt < 2; ++mt)
#pragma unroll
                for (int nt = 0; nt < 4; ++nt)
                    acc[mt][nt] = __builtin_amdgcn_mfma_f32_16x16x32_bf16(
                        af[mt], bfr[nt], acc[mt][nt], 0, 0, 0);
        }
    }

    if (QKV) {
        if (sel < 2) {
            unsigned short* Hb = sel ? KbO : QbO;
            float2* dst2 = sel ? knckO : qnc2O;
            const int hh = bnl >> 6;   // one head per block (64 cols)
#pragma unroll
            for (int mt = 0; mt < 2; ++mt) {
#pragma unroll
                for (int rg = 0; rg < 4; ++rg) {
                    float ss = 0.f;
#pragma unroll
                    for (int nt = 0; nt < 4; ++nt) {
                        const float v = acc[mt][nt][rg];
                        ss = fmaf(v, v, ss);
                        Hb[(size_t)(bm + wm + mt * 16 + g * 4 + rg) * 1024 +
                           bnl + nt * 16 + r] = f2bf(v);
                    }
                    ss += __shfl_xor(ss, 1, 64);
                    ss += __shfl_xor(ss, 2, 64);
                    ss += __shfl_xor(ss, 4, 64);
                    ss += __shfl_xor(ss, 8, 64);
                    if (r == 0) {
                        const int row = bm + wm + mt * 16 + g * 4 + rg;
                        dst2[hh * NSEQ + row] =
                            make_float2(ss, (sel ? 1.0f : 2.0f) / (1.0f - ss));
                    }
                }
            }
        } else {
            // V: write transposed bf16 directly (Vt[(h*64+d)][n])
#pragma unroll
            for (int mt = 0; mt < 2; ++mt)
#pragma unroll
                for (int nt = 0; nt < 4; ++nt) {
                    ushort4 o4;
                    o4.x = f2bf(acc[mt][nt][0]);
                    o4.y = f2bf(acc[mt][nt][1]);
                    o4.z = f2bf(acc[mt][nt][2]);
                    o4.w = f2bf(acc[mt][nt][3]);
                    *reinterpret_cast<ushort4*>(
                        &VtO[(size_t)(bnl + nt * 16 + r) * NSEQ +
                             bm + wm + mt * 16 + g * 4]) = o4;
                }
        }
    } else {
#pragma unroll
        for (int mt = 0; mt < 2; ++mt)
#pragma unroll
            for (int nt = 0; nt < 4; ++nt)
#pragma unroll
                for (int rg = 0; rg < 4; ++rg)
                    C0[(size_t)(bm + wm + mt * 16 + g * 4 + rg) * 1024 +
                       bnl + nt * 16 + r] = acc[mt][nt][rg];
    }
}

// ---------------------------------------------------------------------------
// MFMA hyperbolic attention v8 = R12's v5 (53.8us measured) with kn/ck
// packed as float2 (one b64 LDS read per jt instead of two b32).
// Grid (NSEQ/64, NHEADS, NJH). 4 waves; wave w: q rows [n0+16w,+16).
// ---------------------------------------------------------------------------
__global__ __launch_bounds__(256) void hyp_attn_v8(
    const unsigned short* __restrict__ Qb, const unsigned short* __restrict__ Kb,
    const unsigned short* __restrict__ Vt,
    const float2* __restrict__ qnc2_a, const float2* __restrict__ knck_a,
    float* __restrict__ Opart, float* __restrict__ lpart)
{
    __shared__ unsigned short Khs[64 * 64];   // [j][k-seg swz]
    __shared__ unsigned short Vts[64 * 64];   // [d][j-seg swz]
    __shared__ unsigned short Ps[4][16 * 64]; // per-wave [q][j-seg swz]
    __shared__ float2 kcs[JSPAN];             // {kn, ck} per j

    const int h    = blockIdx.y;
    const int n0   = blockIdx.x * 64;
    const int jh   = blockIdx.z;
    const int t    = threadIdx.x;
    const int wid  = t >> 6;
    const int lane = t & 63;
    const int g    = lane >> 4;
    const int r    = lane & 15;
    const int qb   = n0 + wid * 16;

    // ---- prologue: Q frags, per-q constants, kn/ck span -> LDS ----
    bf16x8 qf[2];
#pragma unroll
    for (int dc = 0; dc < 2; ++dc)
        qf[dc] = *reinterpret_cast<const bf16x8*>(
            Qb + (size_t)(qb + r) * DMODEL + h * HD + dc * 32 + g * 8);

    float qn_r[4], c2q[4];
#pragma unroll
    for (int rg = 0; rg < 4; ++rg) {
        const float2 qv = qnc2_a[h * NSEQ + qb + g * 4 + rg];
        qn_r[rg] = qv.x;
        c2q[rg]  = qv.y;
    }
#pragma unroll
    for (int i = 0; i < JSPAN / 256; ++i)
        kcs[i * 256 + t] = knck_a[h * NSEQ + jh * JSPAN + i * 256 + t];

    f32x4 oacc[4];
#pragma unroll
    for (int nt = 0; nt < 4; ++nt) oacc[nt] = (f32x4){0.f, 0.f, 0.f, 0.f};
    float l_acc[4] = {0.f, 0.f, 0.f, 0.f};

    const int srow = t >> 2;
    const int c0   = (t & 3) * 2;
    const int sw0  = (c0 ^ (srow & 7)) * 8;
    const int sw1  = ((c0 + 1) ^ (srow & 7)) * 8;
    const int sg   = (t & 3) * 16;
    unsigned short* Pw = &Ps[wid][0];

    const unsigned short* Kg = Kb + (size_t)(jh * JSPAN + srow) * DMODEL + h * HD + sg;
    const unsigned short* Vg = Vt + (size_t)(h * HD + srow) * NSEQ + jh * JSPAN + sg;

    // prefetch tile 0 into regs
    ushort8_t kr0 = *reinterpret_cast<const ushort8_t*>(Kg);
    ushort8_t kr1 = *reinterpret_cast<const ushort8_t*>(Kg + 8);
    ushort8_t vr0 = *reinterpret_cast<const ushort8_t*>(Vg);
    ushort8_t vr1 = *reinterpret_cast<const ushort8_t*>(Vg + 8);

    const int ntb = JSPAN / 64;
    for (int tb = 0; tb < ntb; ++tb) {
        __syncthreads();   // prev tile consumed; (tb=0) kcs visible
        *reinterpret_cast<ushort8_t*>(&Khs[srow * 64 + sw0]) = kr0;
        *reinterpret_cast<ushort8_t*>(&Khs[srow * 64 + sw1]) = kr1;
        *reinterpret_cast<ushort8_t*>(&Vts[srow * 64 + sw0]) = vr0;
        *reinterpret_cast<ushort8_t*>(&Vts[srow * 64 + sw1]) = vr1;
        if (tb + 1 < ntb) {   // T14: next-tile loads overlap with compute
            const unsigned short* kn_ = Kg + (size_t)(tb + 1) * 64 * DMODEL;
            const unsigned short* vn_ = Vg + (tb + 1) * 64;
            kr0 = *reinterpret_cast<const ushort8_t*>(kn_);
            kr1 = *reinterpret_cast<const ushort8_t*>(kn_ + 8);
            vr0 = *reinterpret_cast<const ushort8_t*>(vn_);
            vr1 = *reinterpret_cast<const ushort8_t*>(vn_ + 8);
        }
        __syncthreads();

        // ---- S tiles + distance -> w -> P (swizzled wave-private LDS) ----
#pragma unroll
        for (int jt = 0; jt < 4; ++jt) {
            f32x4 sac = (f32x4){0.f, 0.f, 0.f, 0.f};
#pragma unroll
            for (int dc = 0; dc < 2; ++dc) {
                const bf16x8 kb = *reinterpret_cast<const bf16x8*>(
                    &Khs[(jt * 16 + r) * 64 + ((dc * 4 + g) ^ (r & 7)) * 8]);
                sac = __builtin_amdgcn_mfma_f32_16x16x32_bf16(qf[dc], kb, sac, 0, 0, 0);
            }
            const float2 kc = kcs[tb * 64 + jt * 16 + r];
#pragma unroll
            for (int rg = 0; rg < 4; ++rg) {
                const float dsq = fmaf(-2.f, sac[rg], qn_r[rg] + kc.x);
                const float ca  = fmaxf(fmaf(dsq, c2q[rg] * kc.y, 1.f), 1.0f);
                const float s2  = fmaf(ca, ca, -1.f);
                const float wj  = ca - __builtin_amdgcn_sqrtf(s2);
                l_acc[rg] += wj;
                const int qrow = g * 4 + rg;
                Pw[qrow * 64 +
                   ((2 * jt + (r >> 3)) ^ (qrow & 7)) * 8 + (r & 7)] = f2bf(wj);
            }
        }
        // Pw is wave-private: within-wave ds ordering suffices

        // ---- PV: O[q][d] += P . V ----
#pragma unroll
        for (int kc2 = 0; kc2 < 2; ++kc2) {
            const bf16x8 pa = *reinterpret_cast<const bf16x8*>(
                &Pw[r * 64 + ((kc2 * 4 + g) ^ (r & 7)) * 8]);
#pragma unroll
            for (int nt = 0; nt < 4; ++nt) {
                const bf16x8 vb = *reinterpret_cast<const bf16x8*>(
                    &Vts[(nt * 16 + r) * 64 + ((kc2 * 4 + g) ^ (r & 7)) * 8]);
                oacc[nt] = __builtin_amdgcn_mfma_f32_16x16x32_bf16(pa, vb, oacc[nt], 0, 0, 0);
            }
        }
    }

    // ---- l reduce over the 16 r-lanes ----
#pragma unroll
    for (int rg = 0; rg < 4; ++rg) {
        l_acc[rg] += __shfl_xor(l_acc[rg], 1, 64);
        l_acc[rg] += __shfl_xor(l_acc[rg], 2, 64);
        l_acc[rg] += __shfl_xor(l_acc[rg], 4, 64);
        l_acc[rg] += __shfl_xor(l_acc[rg], 8, 64);
    }

    // ---- write partials ----
    float* Op = Opart + (size_t)jh * NSEQ * DMODEL;
#pragma unroll
    for (int nt = 0; nt < 4; ++nt)
#pragma unroll
        for (int rg = 0; rg < 4; ++rg)
            Op[(size_t)(qb + g * 4 + rg) * DMODEL + h * HD + nt * 16 + r] =
                oacc[nt][rg];
    if (r == 0) {
#pragma unroll
        for (int rg = 0; rg < 4; ++rg)
            lpart[(jh * NHEADS + h) * NSEQ + qb + g * 4 + rg] = l_acc[rg];
    }
}

// ---------------------------------------------------------------------------
// Merge j-split partials: Ob = bf16((O0+O1) / (l0+l1)).
// ---------------------------------------------------------------------------
__global__ __launch_bounds__(256) void merge_kernel(
    const float* __restrict__ Opart, const float* __restrict__ lpart,
    unsigned short* __restrict__ Ob)
{
    const size_t i8 = ((size_t)blockIdx.x * 256 + threadIdx.x) * 8;
    if (i8 >= (size_t)NSEQ * DMODEL) return;
    const int n  = (int)(i8 >> 10);
    const int dm = (int)(i8 & 1023);
    const int h  = dm >> 6;
    const float li = 1.0f / (lpart[h * NSEQ + n] +
                             lpart[(NHEADS + h) * NSEQ + n]);
    const float* O0 = Opart + i8;
    const float* O1 = Opart + (size_t)NSEQ * DMODEL + i8;
    ushort8_t o;
#pragma unroll
    for (int c = 0; c < 2; ++c) {
        const float4 a = *reinterpret_cast<const float4*>(O0 + c * 4);
        const float4 b = *reinterpret_cast<const float4*>(O1 + c * 4);
        o[c * 4 + 0] = f2bf((a.x + b.x) * li);
        o[c * 4 + 1] = f2bf((a.y + b.y) * li);
        o[c * 4 + 2] = f2bf((a.z + b.z) * li);
        o[c * 4 + 3] = f2bf((a.w + b.w) * li);
    }
    *reinterpret_cast<ushort8_t*>(Ob + i8) = o;
}

// ---------------------------------------------------------------------------
extern "C" void kernel_launch(void* const* d_in, const int* in_sizes, int n_in,
                              void* d_out, int out_size, void* d_ws, size_t ws_size,
                              hipStream_t stream)
{
    const float* x  = (const float*)d_in[0];
    const float* Wq = (const float*)d_in[1];
    const float* Wk = (const float*)d_in[2];
    const float* Wv = (const float*)d_in[3];
    const float* Wo = (const float*)d_in[4];
    float* out = (float*)d_out;

    char* ws = (char*)d_ws;
    const size_t MB = 1048576;
    unsigned short* xb   = (unsigned short*)(ws);             // 4MB (-> Ob)
    unsigned short* Wb   = (unsigned short*)(ws + 4  * MB);   // 6MB
    unsigned short* Wob  = (unsigned short*)(ws + 10 * MB);   // 2MB
    unsigned short* Qbuf = (unsigned short*)(ws + 12 * MB);   // 4MB
    unsigned short* Kbuf = (unsigned short*)(ws + 16 * MB);   // 4MB
    unsigned short* Vt   = (unsigned short*)(ws + 20 * MB);   // 4MB
    float2*         qnc2 = (float2*)(ws + 24 * MB);           // 256KB
    float2*         knck = (float2*)(ws + 24 * MB + 262144);  // 256KB
    float*          Opart= (float*)(ws + 25 * MB);            // 16MB
    float*          lpart= (float*)(ws + 41 * MB);            // 256KB
    unsigned short* Ob   = xb;   // xb dead after QKV GEMM

    const dim3 blk(256);

    // 1. fp32 -> bf16 conversions
    convert_inputs<<<3072, blk, 0, stream>>>(x, Wq, Wk, Wv, Wo, xb, Wb, Wob);

    // 2. fused QKV projection + norms + V-transpose in epilogue  [768 blocks]
    gemm_bt_bf16<1><<<dim3(NSEQ / 128, 3072 / 64), blk, 0, stream>>>(
        xb, Wb, nullptr, Qbuf, qnc2, Kbuf, knck, Vt);

    // 3. attention partials (j-split x2, T14 pipeline)  [1024 blocks]
    hyp_attn_v8<<<dim3(NSEQ / 64, NHEADS, NJH), blk, 0, stream>>>(
        Qbuf, Kbuf, Vt, qnc2, knck, Opart, lpart);

    // 4. merge partials -> Ob (bf16)
    merge_kernel<<<(NSEQ * DMODEL / 8 + 255) / 256, blk, 0, stream>>>(
        Opart, lpart, Ob);

    // 5. output projection  [256 blocks]
    gemm_bt_bf16<0><<<dim3(NSEQ / 128, DMODEL / 64), blk, 0, stream>>>(
        Ob, Wob, out, nullptr, nullptr, nullptr, nullptr, nullptr);
}